// Round 6
// baseline (725.183 us; speedup 1.0000x reference)
//
#include <hip/hip_runtime.h>
#include <hip/hip_fp16.h>

#define NN 100000
#define NE 1600000
#define NG 2000
#define DIM 256
#define NF 4
#define SCAN_B 1024
#define NBLK ((NN + SCAN_B - 1) / SCAN_B)   // 98
#define CNT_BLK 2048
#define EMB_BLK ((NN * 64) / 256)           // 25000
#define SCAT_BLK 2048
#define WCONV_BLK 256

using half8 = __attribute__((ext_vector_type(8))) _Float16;
using f32x4 = __attribute__((ext_vector_type(4))) float;

__device__ inline float4 h4_to_f4(uint2 v) {
    __half2 a = *reinterpret_cast<__half2*>(&v.x);
    __half2 b = *reinterpret_cast<__half2*>(&v.y);
    float2 fa = __half22float2(a);
    float2 fb = __half22float2(b);
    return make_float4(fa.x, fa.y, fb.x, fb.y);
}

__device__ inline uint2 f4_to_h4(float4 r) {
    __half2 a = __floats2half2_rn(r.x, r.y);
    __half2 b = __floats2half2_rn(r.z, r.w);
    uint2 o;
    o.x = *reinterpret_cast<uint*>(&a);
    o.y = *reinterpret_cast<uint*>(&b);
    return o;
}

// ---------------- FUSED: degree counting + slot capture | embedding sum ----------------
// blocks [0, CNT_BLK): histogram src->outd, dst->ind (slot = old ind value, ushort).
// blocks [CNT_BLK, CNT_BLK+EMB_BLK): h0[node] = sum_f emb[feat[node][f]]  (fp16, NO onorm)
__global__ void k_count_embed(const int* __restrict__ src, const int* __restrict__ dst,
                              int* __restrict__ outd, int* __restrict__ ind,
                              ushort* __restrict__ slots,
                              const int* __restrict__ feat, const float* __restrict__ emb,
                              ushort* __restrict__ h) {
    int tid = threadIdx.x;
    if (blockIdx.x < CNT_BLK) {
        int i = blockIdx.x * 256 + tid;
        const int stride = CNT_BLK * 256;
        for (; i < NE; i += stride) {
            atomicAdd(&outd[src[i]], 1);
            int s = atomicAdd(&ind[dst[i]], 1);
            slots[i] = (ushort)s;
        }
    } else {
        int idx = (blockIdx.x - CNT_BLK) * 256 + tid;  // NN*64 total
        int node = idx >> 6;
        int g = idx & 63;
        if (node >= NN) return;
        const int4 f = *reinterpret_cast<const int4*>(feat + node * 4);
        const float4* emb4 = reinterpret_cast<const float4*>(emb);
        float4 a = emb4[(long)f.x * 64 + g];
        float4 b = emb4[(long)f.y * 64 + g];
        float4 c = emb4[(long)f.z * 64 + g];
        float4 d = emb4[(long)f.w * 64 + g];
        float4 r;
        r.x = (a.x + b.x) + (c.x + d.x);
        r.y = (a.y + b.y) + (c.y + d.y);
        r.z = (a.z + b.z) + (c.z + d.z);
        r.w = (a.w + b.w) + (c.w + d.w);
        reinterpret_cast<uint2*>(h)[(long)node * 64 + g] = f4_to_h4(r);
    }
}

// ---------------- multi-block exclusive scan of in-degrees ----------------
__global__ __launch_bounds__(1024) void k_scan1(const int* __restrict__ deg,
                                                int* __restrict__ locex,
                                                int* __restrict__ partials) {
    __shared__ int sm[SCAN_B];
    int t = threadIdx.x;
    int i = blockIdx.x * SCAN_B + t;
    int v = (i < NN) ? deg[i] : 0;
    sm[t] = v;
    __syncthreads();
    for (int off = 1; off < SCAN_B; off <<= 1) {
        int u = (t >= off) ? sm[t - off] : 0;
        __syncthreads();
        sm[t] += u;
        __syncthreads();
    }
    if (i < NN) locex[i] = sm[t] - v;
    if (t == SCAN_B - 1) partials[blockIdx.x] = sm[t];
}

__global__ __launch_bounds__(128) void k_scan2(int* __restrict__ partials,
                                               int* __restrict__ rowptr_last) {
    __shared__ int sm[128];
    int t = threadIdx.x;
    int v = (t < NBLK) ? partials[t] : 0;
    sm[t] = v;
    __syncthreads();
    for (int off = 1; off < 128; off <<= 1) {
        int u = (t >= off) ? sm[t - off] : 0;
        __syncthreads();
        sm[t] += u;
        __syncthreads();
    }
    if (t < NBLK) partials[t] = sm[t] - v;
    if (t == 127) *rowptr_last = sm[127];
}

// phase 3: rowptr = locex + block offset; also compute norms (fused per-node pass)
__global__ __launch_bounds__(1024) void k_scan3(const int* __restrict__ locex,
                                                const int* __restrict__ partials,
                                                const int* __restrict__ outd,
                                                const int* __restrict__ ind,
                                                int* __restrict__ rowptr,
                                                float* __restrict__ onorm,
                                                float* __restrict__ inorm) {
    int i = blockIdx.x * SCAN_B + threadIdx.x;
    if (i < NN) {
        rowptr[i] = locex[i] + partials[blockIdx.x];
        int od = outd[i];
        int id = ind[i];
        onorm[i] = od > 0 ? rsqrtf((float)od) : 0.f;
        inorm[i] = id > 0 ? rsqrtf((float)id) : 0.f;
    }
}

// ---------------- FUSED: atomic-free scatter | W -> Wt fp16 transpose ----------------
__global__ void k_scatter_wconv(const int* __restrict__ src, const int* __restrict__ dst,
                                const int* __restrict__ rowptr, const ushort* __restrict__ slots,
                                int* __restrict__ col,
                                const float* __restrict__ W1, const float* __restrict__ W2,
                                ushort* __restrict__ Wt1, ushort* __restrict__ Wt2) {
    int tid = threadIdx.x;
    if (blockIdx.x < SCAT_BLK) {
        int i = blockIdx.x * 256 + tid;
        const int stride = SCAT_BLK * 256;
        for (; i < NE; i += stride) {
            int d = dst[i];
            col[rowptr[d] + (int)slots[i]] = src[i];
        }
    } else {
        int idx = (blockIdx.x - SCAT_BLK) * 256 + tid;  // 65536
        if (idx >= DIM * DIM) return;
        int k = idx >> 8;
        int n = idx & 255;
        __fp16 a = (__fp16)W1[idx];
        __fp16 b = (__fp16)W2[idx];
        reinterpret_cast<__fp16*>(Wt1)[n * DIM + k] = a;
        reinterpret_cast<__fp16*>(Wt2)[n * DIM + k] = b;
    }
}

// ---------------- aggregation: one wave per dst node ----------------
// 16B/lane loads: lanes 0-31 fetch even edges' rows, lanes 32-63 odd edges'.
// SCALE=1: gather-side multiply by onorm[src] (layer 0, h0 stored unscaled).
// MODE 0: hout = relu(acc * inorm) * onorm ; MODE 1: hout = acc * inorm
template <int MODE, int SCALE>
__global__ void k_agg(const int* __restrict__ rowptr, const int* __restrict__ col,
                      const ushort* __restrict__ hin, const float* __restrict__ inorm,
                      const float* __restrict__ onorm, ushort* __restrict__ hout) {
    int wid = (blockIdx.x * blockDim.x + threadIdx.x) >> 6;
    int lane = threadIdx.x & 63;
    if (wid >= NN) return;
    int half = lane >> 5;
    int l32 = lane & 31;
    int e0 = rowptr[wid];
    int e1 = rowptr[wid + 1];
    const uint4* hin4 = reinterpret_cast<const uint4*>(hin);
    float4 aA0 = {0,0,0,0}, aA1 = {0,0,0,0};
    float4 aB0 = {0,0,0,0}, aB1 = {0,0,0,0};
    int e = e0;
    // main: 16 edges per iter, 8 independent 16B gathers per lane in flight
    for (; e + 16 <= e1; e += 16) {
        int s0 = col[e + 0 + half];
        int s1 = col[e + 2 + half];
        int s2 = col[e + 4 + half];
        int s3 = col[e + 6 + half];
        int s4 = col[e + 8 + half];
        int s5 = col[e + 10 + half];
        int s6 = col[e + 12 + half];
        int s7 = col[e + 14 + half];
        uint4 u0 = hin4[(long)s0 * 32 + l32];
        uint4 u1 = hin4[(long)s1 * 32 + l32];
        uint4 u2 = hin4[(long)s2 * 32 + l32];
        uint4 u3 = hin4[(long)s3 * 32 + l32];
        uint4 u4 = hin4[(long)s4 * 32 + l32];
        uint4 u5 = hin4[(long)s5 * 32 + l32];
        uint4 u6 = hin4[(long)s6 * 32 + l32];
        uint4 u7 = hin4[(long)s7 * 32 + l32];
        float os0 = 1.f, os1 = 1.f, os2 = 1.f, os3 = 1.f;
        float os4 = 1.f, os5 = 1.f, os6 = 1.f, os7 = 1.f;
        if (SCALE) {
            os0 = onorm[s0]; os1 = onorm[s1]; os2 = onorm[s2]; os3 = onorm[s3];
            os4 = onorm[s4]; os5 = onorm[s5]; os6 = onorm[s6]; os7 = onorm[s7];
        }
        uint2 lo, hi;
        float4 v;
#define ACC8(U, OS, A0, A1)                                            \
        lo.x = U.x; lo.y = U.y; hi.x = U.z; hi.y = U.w;                \
        v = h4_to_f4(lo);                                              \
        if (SCALE) { v.x *= OS; v.y *= OS; v.z *= OS; v.w *= OS; }     \
        A0.x += v.x; A0.y += v.y; A0.z += v.z; A0.w += v.w;            \
        v = h4_to_f4(hi);                                              \
        if (SCALE) { v.x *= OS; v.y *= OS; v.z *= OS; v.w *= OS; }     \
        A1.x += v.x; A1.y += v.y; A1.z += v.z; A1.w += v.w;
        ACC8(u0, os0, aA0, aA1)
        ACC8(u1, os1, aB0, aB1)
        ACC8(u2, os2, aA0, aA1)
        ACC8(u3, os3, aB0, aB1)
        ACC8(u4, os4, aA0, aA1)
        ACC8(u5, os5, aB0, aB1)
        ACC8(u6, os6, aA0, aA1)
        ACC8(u7, os7, aB0, aB1)
    }
    // tail: 2 edges per iter
    for (; e < e1; e += 2) {
        int idx = e + half;
        if (idx < e1) {
            int s = col[idx];
            uint4 u = hin4[(long)s * 32 + l32];
            float os = 1.f;
            if (SCALE) os = onorm[s];
            uint2 lo, hi;
            float4 v;
            ACC8(u, os, aA0, aA1)
        }
    }
#undef ACC8
    float f[8];
    f[0] = aA0.x + aB0.x; f[1] = aA0.y + aB0.y; f[2] = aA0.z + aB0.z; f[3] = aA0.w + aB0.w;
    f[4] = aA1.x + aB1.x; f[5] = aA1.y + aB1.y; f[6] = aA1.z + aB1.z; f[7] = aA1.w + aB1.w;
#pragma unroll
    for (int j = 0; j < 8; ++j) f[j] += __shfl_xor(f[j], 32);

    float sc = inorm[wid];
    float4 r0, r1;
    if (MODE == 0) {
        float on = onorm[wid];
        r0.x = fmaxf(f[0] * sc, 0.f) * on;
        r0.y = fmaxf(f[1] * sc, 0.f) * on;
        r0.z = fmaxf(f[2] * sc, 0.f) * on;
        r0.w = fmaxf(f[3] * sc, 0.f) * on;
        r1.x = fmaxf(f[4] * sc, 0.f) * on;
        r1.y = fmaxf(f[5] * sc, 0.f) * on;
        r1.z = fmaxf(f[6] * sc, 0.f) * on;
        r1.w = fmaxf(f[7] * sc, 0.f) * on;
    } else {
        r0.x = f[0] * sc; r0.y = f[1] * sc; r0.z = f[2] * sc; r0.w = f[3] * sc;
        r1.x = f[4] * sc; r1.y = f[5] * sc; r1.z = f[6] * sc; r1.w = f[7] * sc;
    }
    if (half == 0) {
        uint2 lo = f4_to_h4(r0);
        uint2 hi = f4_to_h4(r1);
        uint4 o; o.x = lo.x; o.y = lo.y; o.z = hi.x; o.w = hi.y;
        reinterpret_cast<uint4*>(hout)[(long)wid * 32 + l32] = o;
    }
}

// ---------------- MFMA GEMM: y[NN,256] = x[NN,256] @ W[256,256] ----------------
// 512 threads (8 waves); wave computes 48 rows (3 m-frags) x 256 cols; block = 384 rows.
__global__ __launch_bounds__(512, 2) void k_gemm(const ushort* __restrict__ x,
                                                 const ushort* __restrict__ Wt,
                                                 ushort* __restrict__ y) {
    __shared__ char wl[131072];
    int tid = threadIdx.x;
    const uint4* Wt4 = reinterpret_cast<const uint4*>(Wt);
#pragma unroll
    for (int it = 0; it < 16; ++it) {
        int chunk = it * 512 + tid;      // 0..8191 16B-chunks
        int n = chunk >> 5;              // row 0..255
        int c16 = chunk & 31;
        uint4 v = Wt4[chunk];
        int off = ((n << 9) + (c16 << 4)) ^ ((n & 7) << 4);
        *reinterpret_cast<uint4*>(&wl[off]) = v;
    }
    __syncthreads();

    int w = tid >> 6;
    int l = tid & 63;
    int wrow = blockIdx.x * 384 + w * 48;
    int lrow = l & 15;
    int lk = l >> 4;

    f32x4 acc[3][16];
#pragma unroll
    for (int m = 0; m < 3; ++m)
#pragma unroll
        for (int n = 0; n < 16; ++n) acc[m][n] = {0.f, 0.f, 0.f, 0.f};

    const char* xb = reinterpret_cast<const char*>(x);
    int r0 = wrow + lrow;
    int r1 = r0 + 16;
    int r2 = r0 + 32;
    r0 = r0 < NN ? r0 : NN - 1;
    r1 = r1 < NN ? r1 : NN - 1;
    r2 = r2 < NN ? r2 : NN - 1;

#pragma unroll
    for (int ks = 0; ks < DIM; ks += 32) {
        long kbyte = (long)(ks + lk * 8) * 2;
        half8 a0 = *reinterpret_cast<const half8*>(xb + (long)r0 * 512 + kbyte);
        half8 a1 = *reinterpret_cast<const half8*>(xb + (long)r1 * 512 + kbyte);
        half8 a2 = *reinterpret_cast<const half8*>(xb + (long)r2 * 512 + kbyte);
#pragma unroll
        for (int fn = 0; fn < 16; ++fn) {
            int n = fn * 16 + lrow;
            int off = ((n << 9) + (int)kbyte) ^ ((n & 7) << 4);
            half8 b = *reinterpret_cast<const half8*>(&wl[off]);
            acc[0][fn] = __builtin_amdgcn_mfma_f32_16x16x32_f16(a0, b, acc[0][fn], 0, 0, 0);
            acc[1][fn] = __builtin_amdgcn_mfma_f32_16x16x32_f16(a1, b, acc[1][fn], 0, 0, 0);
            acc[2][fn] = __builtin_amdgcn_mfma_f32_16x16x32_f16(a2, b, acc[2][fn], 0, 0, 0);
        }
    }

    __fp16* yh = reinterpret_cast<__fp16*>(y);
#pragma unroll
    for (int m = 0; m < 3; ++m) {
        int rbase = wrow + m * 16 + lk * 4;
#pragma unroll
        for (int fn = 0; fn < 16; ++fn) {
            int colc = fn * 16 + lrow;
#pragma unroll
            for (int r = 0; r < 4; ++r) {
                int row = rbase + r;
                if (row < NN) yh[(long)row * DIM + colc] = (__fp16)acc[m][fn][r];
            }
        }
    }
}

// ---------------- per-graph sum pooling (graph_ids sorted) ----------------
__device__ inline int lbound(const int* __restrict__ a, int n, int v) {
    int lo = 0, hi = n;
    while (lo < hi) {
        int m = (lo + hi) >> 1;
        if (a[m] < v) lo = m + 1; else hi = m;
    }
    return lo;
}

__global__ __launch_bounds__(256) void k_pool(const ushort* __restrict__ h,
                                              const int* __restrict__ gids,
                                              float* __restrict__ out) {
    int g = blockIdx.x;
    int t = threadIdx.x;
    int lo = lbound(gids, NN, g);
    int hi = lbound(gids, NN, g + 1);
    const __fp16* hh = reinterpret_cast<const __fp16*>(h);
    float acc = 0.f;
    for (int nd = lo; nd < hi; ++nd) acc += (float)hh[(long)nd * DIM + t];
    out[(long)g * DIM + t] = acc;
}

extern "C" void kernel_launch(void* const* d_in, const int* in_sizes, int n_in,
                              void* d_out, int out_size, void* d_ws, size_t ws_size,
                              hipStream_t stream) {
    const int* feature = (const int*)d_in[0];
    const int* src = (const int*)d_in[1];
    const int* dst = (const int*)d_in[2];
    const int* gids = (const int*)d_in[3];
    const float* emb = (const float*)d_in[4];
    const float* W1 = (const float*)d_in[5];
    const float* W2 = (const float*)d_in[6];
    float* out = (float*)d_out;

    // workspace carve (all 16B aligned)
    char* p = (char*)d_ws;
    ushort* hA = (ushort*)p;            p += (size_t)NN * DIM * 2;
    ushort* hB = (ushort*)p;            p += (size_t)NN * DIM * 2;
    ushort* Wt1 = (ushort*)p;           p += (size_t)DIM * DIM * 2;
    ushort* Wt2 = (ushort*)p;           p += (size_t)DIM * DIM * 2;
    float* onorm = (float*)p;           p += (size_t)NN * 4;
    float* inorm = (float*)p;           p += (size_t)NN * 4;
    int* rowptr = (int*)p;              p += (size_t)(NN + 4) * 4;
    int* colidx = (int*)p;              p += (size_t)NE * 4;
    int* outd = (int*)p;                p += (size_t)NN * 4;
    int* ind = (int*)p;                 p += (size_t)NN * 4;
    int* locex = (int*)p;               p += (size_t)NN * 4;
    int* partials = (int*)p;            p += (size_t)128 * 4;
    ushort* slots = (ushort*)p;         p += (size_t)NE * 2;

    hipMemsetAsync(outd, 0, (size_t)2 * NN * 4, stream);  // outd | ind contiguous

    // fused: histogram (+slots) | embedding sum (h0 unscaled)
    k_count_embed<<<CNT_BLK + EMB_BLK, 256, 0, stream>>>(src, dst, outd, ind, slots,
                                                         feature, emb, hA);
    k_scan1<<<NBLK, SCAN_B, 0, stream>>>(ind, locex, partials);
    k_scan2<<<1, 128, 0, stream>>>(partials, rowptr + NN);
    k_scan3<<<NBLK, SCAN_B, 0, stream>>>(locex, partials, outd, ind, rowptr, onorm, inorm);
    // fused: scatter | weight transpose+fp16
    k_scatter_wconv<<<SCAT_BLK + WCONV_BLK, 256, 0, stream>>>(src, dst, rowptr, slots, colidx,
                                                              W1, W2, Wt1, Wt2);

    const int aggGrid = (NN * 64 + 255) / 256;
    const int gemmGrid = (NN + 383) / 384;
    // layer 0 (no W): hB = relu(agg(hA * onorm_src) * inorm) * onorm   (gather-side scale)
    k_agg<0, 1><<<aggGrid, 256, 0, stream>>>(rowptr, colidx, hA, inorm, onorm, hB);
    // layer 1: hA = hB @ W1 ; hB = relu(agg(hA) * inorm) * onorm
    k_gemm<<<gemmGrid, 512, 0, stream>>>(hB, Wt1, hA);
    k_agg<0, 0><<<aggGrid, 256, 0, stream>>>(rowptr, colidx, hA, inorm, onorm, hB);
    // layer 2: hA = hB @ W2 ; hB = agg(hA) * inorm
    k_gemm<<<gemmGrid, 512, 0, stream>>>(hB, Wt2, hA);
    k_agg<1, 0><<<aggGrid, 256, 0, stream>>>(rowptr, colidx, hA, inorm, onorm, hB);
    // pool per graph
    k_pool<<<NG, 256, 0, stream>>>(hB, gids, out);
}

// Round 7
// 661.566 us; speedup vs baseline: 1.0962x; 1.0962x over previous
//
#include <hip/hip_runtime.h>
#include <hip/hip_fp16.h>

#define NN 100000
#define NE 1600000
#define NG 2000
#define DIM 256
#define NF 4
#define SCAN_B 1024
#define NBLK ((NN + SCAN_B - 1) / SCAN_B)   // 98
#define SCAT_BLK 2048
#define WCONV_BLK 256

using half8 = __attribute__((ext_vector_type(8))) _Float16;
using f32x4 = __attribute__((ext_vector_type(4))) float;

__device__ inline float4 h4_to_f4(uint2 v) {
    __half2 a = *reinterpret_cast<__half2*>(&v.x);
    __half2 b = *reinterpret_cast<__half2*>(&v.y);
    float2 fa = __half22float2(a);
    float2 fb = __half22float2(b);
    return make_float4(fa.x, fa.y, fb.x, fb.y);
}

__device__ inline uint2 f4_to_h4(float4 r) {
    __half2 a = __floats2half2_rn(r.x, r.y);
    __half2 b = __floats2half2_rn(r.z, r.w);
    uint2 o;
    o.x = *reinterpret_cast<uint*>(&a);
    o.y = *reinterpret_cast<uint*>(&b);
    return o;
}

__device__ inline void add8(float4& a0, float4& a1, uint4 u) {
    uint2 lo2; lo2.x = u.x; lo2.y = u.y;
    uint2 hi2; hi2.x = u.z; hi2.y = u.w;
    float4 lo = h4_to_f4(lo2);
    float4 hi = h4_to_f4(hi2);
    a0.x += lo.x; a0.y += lo.y; a0.z += lo.z; a0.w += lo.w;
    a1.x += hi.x; a1.y += hi.y; a1.z += hi.z; a1.w += hi.w;
}

// ---------------- degree counting + slot capture ----------------
__global__ void k_count(const int* __restrict__ src, const int* __restrict__ dst,
                        int* __restrict__ outd, int* __restrict__ ind,
                        ushort* __restrict__ slots) {
    int i = blockIdx.x * blockDim.x + threadIdx.x;
    int stride = gridDim.x * blockDim.x;
    for (; i < NE; i += stride) {
        atomicAdd(&outd[src[i]], 1);
        int s = atomicAdd(&ind[dst[i]], 1);
        slots[i] = (ushort)s;
    }
}

// ---------------- multi-block exclusive scan of in-degrees ----------------
__global__ __launch_bounds__(1024) void k_scan1(const int* __restrict__ deg,
                                                int* __restrict__ locex,
                                                int* __restrict__ partials) {
    __shared__ int sm[SCAN_B];
    int t = threadIdx.x;
    int i = blockIdx.x * SCAN_B + t;
    int v = (i < NN) ? deg[i] : 0;
    sm[t] = v;
    __syncthreads();
    for (int off = 1; off < SCAN_B; off <<= 1) {
        int u = (t >= off) ? sm[t - off] : 0;
        __syncthreads();
        sm[t] += u;
        __syncthreads();
    }
    if (i < NN) locex[i] = sm[t] - v;
    if (t == SCAN_B - 1) partials[blockIdx.x] = sm[t];
}

__global__ __launch_bounds__(128) void k_scan2(int* __restrict__ partials,
                                               int* __restrict__ rowptr_last) {
    __shared__ int sm[128];
    int t = threadIdx.x;
    int v = (t < NBLK) ? partials[t] : 0;
    sm[t] = v;
    __syncthreads();
    for (int off = 1; off < 128; off <<= 1) {
        int u = (t >= off) ? sm[t - off] : 0;
        __syncthreads();
        sm[t] += u;
        __syncthreads();
    }
    if (t < NBLK) partials[t] = sm[t] - v;
    if (t == 127) *rowptr_last = sm[127];
}

// phase 3: rowptr = locex + block offset; norms fused (per-node pass)
__global__ __launch_bounds__(1024) void k_scan3(const int* __restrict__ locex,
                                                const int* __restrict__ partials,
                                                const int* __restrict__ outd,
                                                const int* __restrict__ ind,
                                                int* __restrict__ rowptr,
                                                float* __restrict__ onorm,
                                                float* __restrict__ inorm) {
    int i = blockIdx.x * SCAN_B + threadIdx.x;
    if (i < NN) {
        rowptr[i] = locex[i] + partials[blockIdx.x];
        int od = outd[i];
        int id = ind[i];
        onorm[i] = od > 0 ? rsqrtf((float)od) : 0.f;
        inorm[i] = id > 0 ? rsqrtf((float)id) : 0.f;
    }
}

// ---------------- FUSED: atomic-free scatter | W -> Wt fp16 transpose ----------------
__global__ void k_scatter_wconv(const int* __restrict__ src, const int* __restrict__ dst,
                                const int* __restrict__ rowptr, const ushort* __restrict__ slots,
                                int* __restrict__ col,
                                const float* __restrict__ W1, const float* __restrict__ W2,
                                ushort* __restrict__ Wt1, ushort* __restrict__ Wt2) {
    int tid = threadIdx.x;
    if (blockIdx.x < SCAT_BLK) {
        int i = blockIdx.x * 256 + tid;
        const int stride = SCAT_BLK * 256;
        for (; i < NE; i += stride) {
            int d = dst[i];
            col[rowptr[d] + (int)slots[i]] = src[i];
        }
    } else {
        int idx = (blockIdx.x - SCAT_BLK) * 256 + tid;  // 65536
        if (idx >= DIM * DIM) return;
        int k = idx >> 8;
        int n = idx & 255;
        __fp16 a = (__fp16)W1[idx];
        __fp16 b = (__fp16)W2[idx];
        reinterpret_cast<__fp16*>(Wt1)[n * DIM + k] = a;
        reinterpret_cast<__fp16*>(Wt2)[n * DIM + k] = b;
    }
}

// ---------------- embedding sum + out_norm prescale -> fp16 ----------------
__global__ void k_embed(const int* __restrict__ feat, const float* __restrict__ emb,
                        const float* __restrict__ onorm, ushort* __restrict__ h) {
    int idx = blockIdx.x * blockDim.x + threadIdx.x;  // NN*64 threads
    int node = idx >> 6;
    int g = idx & 63;
    if (node >= NN) return;
    const int4 f = *reinterpret_cast<const int4*>(feat + node * 4);
    const float4* emb4 = reinterpret_cast<const float4*>(emb);
    float4 a = emb4[(long)f.x * 64 + g];
    float4 b = emb4[(long)f.y * 64 + g];
    float4 c = emb4[(long)f.z * 64 + g];
    float4 d = emb4[(long)f.w * 64 + g];
    float sc = onorm[node];
    float4 r;
    r.x = (a.x + b.x + c.x + d.x) * sc;
    r.y = (a.y + b.y + c.y + d.y) * sc;
    r.z = (a.z + b.z + c.z + d.z) * sc;
    r.w = (a.w + b.w + c.w + d.w) * sc;
    reinterpret_cast<uint2*>(h)[(long)node * 64 + g] = f4_to_h4(r);
}

// ---------------- aggregation: one wave per dst node ----------------
// 16B/lane loads: lanes 0-31 fetch even edges' rows, lanes 32-63 odd edges'.
// MODE 0: hout = relu(acc * inorm) * onorm ; MODE 1: hout = acc * inorm
template <int MODE>
__global__ void k_agg(const int* __restrict__ rowptr, const int* __restrict__ col,
                      const ushort* __restrict__ hin, const float* __restrict__ inorm,
                      const float* __restrict__ onorm, ushort* __restrict__ hout) {
    int wid = (blockIdx.x * blockDim.x + threadIdx.x) >> 6;
    int lane = threadIdx.x & 63;
    if (wid >= NN) return;
    int half = lane >> 5;
    int l32 = lane & 31;
    int e0 = rowptr[wid];
    int e1 = rowptr[wid + 1];
    const uint4* hin4 = reinterpret_cast<const uint4*>(hin);
    float4 aA0 = {0,0,0,0}, aA1 = {0,0,0,0};
    float4 aB0 = {0,0,0,0}, aB1 = {0,0,0,0};
    int e = e0;
    for (; e + 8 <= e1; e += 8) {
        int s0 = col[e + 0 + half];
        int s1 = col[e + 2 + half];
        int s2 = col[e + 4 + half];
        int s3 = col[e + 6 + half];
        uint4 u0 = hin4[(long)s0 * 32 + l32];
        uint4 u1 = hin4[(long)s1 * 32 + l32];
        uint4 u2 = hin4[(long)s2 * 32 + l32];
        uint4 u3 = hin4[(long)s3 * 32 + l32];
        add8(aA0, aA1, u0);
        add8(aB0, aB1, u1);
        add8(aA0, aA1, u2);
        add8(aB0, aB1, u3);
    }
    for (; e < e1; e += 2) {
        int idx = e + half;
        if (idx < e1) {
            int s = col[idx];
            uint4 u = hin4[(long)s * 32 + l32];
            add8(aA0, aA1, u);
        }
    }
    float f[8];
    f[0] = aA0.x + aB0.x; f[1] = aA0.y + aB0.y; f[2] = aA0.z + aB0.z; f[3] = aA0.w + aB0.w;
    f[4] = aA1.x + aB1.x; f[5] = aA1.y + aB1.y; f[6] = aA1.z + aB1.z; f[7] = aA1.w + aB1.w;
#pragma unroll
    for (int j = 0; j < 8; ++j) f[j] += __shfl_xor(f[j], 32);

    float sc = inorm[wid];
    float4 r0, r1;
    if (MODE == 0) {
        float on = onorm[wid];
        r0.x = fmaxf(f[0] * sc, 0.f) * on;
        r0.y = fmaxf(f[1] * sc, 0.f) * on;
        r0.z = fmaxf(f[2] * sc, 0.f) * on;
        r0.w = fmaxf(f[3] * sc, 0.f) * on;
        r1.x = fmaxf(f[4] * sc, 0.f) * on;
        r1.y = fmaxf(f[5] * sc, 0.f) * on;
        r1.z = fmaxf(f[6] * sc, 0.f) * on;
        r1.w = fmaxf(f[7] * sc, 0.f) * on;
    } else {
        r0.x = f[0] * sc; r0.y = f[1] * sc; r0.z = f[2] * sc; r0.w = f[3] * sc;
        r1.x = f[4] * sc; r1.y = f[5] * sc; r1.z = f[6] * sc; r1.w = f[7] * sc;
    }
    if (half == 0) {
        uint2 lo = f4_to_h4(r0);
        uint2 hi = f4_to_h4(r1);
        uint4 o; o.x = lo.x; o.y = lo.y; o.z = hi.x; o.w = hi.y;
        reinterpret_cast<uint4*>(hout)[(long)wid * 32 + l32] = o;
    }
}

// ---------------- MFMA GEMM: y[NN,256] = x[NN,256] @ W[256,256] ----------------
// 512 threads (8 waves); wave computes 48 rows (3 m-frags) x 256 cols; block = 384 rows.
__global__ __launch_bounds__(512, 2) void k_gemm(const ushort* __restrict__ x,
                                                 const ushort* __restrict__ Wt,
                                                 ushort* __restrict__ y) {
    __shared__ char wl[131072];
    int tid = threadIdx.x;
    const uint4* Wt4 = reinterpret_cast<const uint4*>(Wt);
#pragma unroll
    for (int it = 0; it < 16; ++it) {
        int chunk = it * 512 + tid;      // 0..8191 16B-chunks
        int n = chunk >> 5;              // row 0..255
        int c16 = chunk & 31;
        uint4 v = Wt4[chunk];
        int off = ((n << 9) + (c16 << 4)) ^ ((n & 7) << 4);
        *reinterpret_cast<uint4*>(&wl[off]) = v;
    }
    __syncthreads();

    int w = tid >> 6;
    int l = tid & 63;
    int wrow = blockIdx.x * 384 + w * 48;
    int lrow = l & 15;
    int lk = l >> 4;

    f32x4 acc[3][16];
#pragma unroll
    for (int m = 0; m < 3; ++m)
#pragma unroll
        for (int n = 0; n < 16; ++n) acc[m][n] = {0.f, 0.f, 0.f, 0.f};

    const char* xb = reinterpret_cast<const char*>(x);
    int r0 = wrow + lrow;
    int r1 = r0 + 16;
    int r2 = r0 + 32;
    r0 = r0 < NN ? r0 : NN - 1;
    r1 = r1 < NN ? r1 : NN - 1;
    r2 = r2 < NN ? r2 : NN - 1;

#pragma unroll
    for (int ks = 0; ks < DIM; ks += 32) {
        long kbyte = (long)(ks + lk * 8) * 2;
        half8 a0 = *reinterpret_cast<const half8*>(xb + (long)r0 * 512 + kbyte);
        half8 a1 = *reinterpret_cast<const half8*>(xb + (long)r1 * 512 + kbyte);
        half8 a2 = *reinterpret_cast<const half8*>(xb + (long)r2 * 512 + kbyte);
#pragma unroll
        for (int fn = 0; fn < 16; ++fn) {
            int n = fn * 16 + lrow;
            int off = ((n << 9) + (int)kbyte) ^ ((n & 7) << 4);
            half8 b = *reinterpret_cast<const half8*>(&wl[off]);
            acc[0][fn] = __builtin_amdgcn_mfma_f32_16x16x32_f16(a0, b, acc[0][fn], 0, 0, 0);
            acc[1][fn] = __builtin_amdgcn_mfma_f32_16x16x32_f16(a1, b, acc[1][fn], 0, 0, 0);
            acc[2][fn] = __builtin_amdgcn_mfma_f32_16x16x32_f16(a2, b, acc[2][fn], 0, 0, 0);
        }
    }

    __fp16* yh = reinterpret_cast<__fp16*>(y);
#pragma unroll
    for (int m = 0; m < 3; ++m) {
        int rbase = wrow + m * 16 + lk * 4;
#pragma unroll
        for (int fn = 0; fn < 16; ++fn) {
            int colc = fn * 16 + lrow;
#pragma unroll
            for (int r = 0; r < 4; ++r) {
                int row = rbase + r;
                if (row < NN) yh[(long)row * DIM + colc] = (__fp16)acc[m][fn][r];
            }
        }
    }
}

// ---------------- per-graph sum pooling (graph_ids sorted) ----------------
__device__ inline int lbound(const int* __restrict__ a, int n, int v) {
    int lo = 0, hi = n;
    while (lo < hi) {
        int m = (lo + hi) >> 1;
        if (a[m] < v) lo = m + 1; else hi = m;
    }
    return lo;
}

__global__ __launch_bounds__(256) void k_pool(const ushort* __restrict__ h,
                                              const int* __restrict__ gids,
                                              float* __restrict__ out) {
    int g = blockIdx.x;
    int t = threadIdx.x;
    int lo = lbound(gids, NN, g);
    int hi = lbound(gids, NN, g + 1);
    const __fp16* hh = reinterpret_cast<const __fp16*>(h);
    float acc = 0.f;
    for (int nd = lo; nd < hi; ++nd) acc += (float)hh[(long)nd * DIM + t];
    out[(long)g * DIM + t] = acc;
}

extern "C" void kernel_launch(void* const* d_in, const int* in_sizes, int n_in,
                              void* d_out, int out_size, void* d_ws, size_t ws_size,
                              hipStream_t stream) {
    const int* feature = (const int*)d_in[0];
    const int* src = (const int*)d_in[1];
    const int* dst = (const int*)d_in[2];
    const int* gids = (const int*)d_in[3];
    const float* emb = (const float*)d_in[4];
    const float* W1 = (const float*)d_in[5];
    const float* W2 = (const float*)d_in[6];
    float* out = (float*)d_out;

    // workspace carve (all 16B aligned)
    char* p = (char*)d_ws;
    ushort* hA = (ushort*)p;            p += (size_t)NN * DIM * 2;
    ushort* hB = (ushort*)p;            p += (size_t)NN * DIM * 2;
    ushort* Wt1 = (ushort*)p;           p += (size_t)DIM * DIM * 2;
    ushort* Wt2 = (ushort*)p;           p += (size_t)DIM * DIM * 2;
    float* onorm = (float*)p;           p += (size_t)NN * 4;
    float* inorm = (float*)p;           p += (size_t)NN * 4;
    int* rowptr = (int*)p;              p += (size_t)(NN + 4) * 4;
    int* colidx = (int*)p;              p += (size_t)NE * 4;
    int* outd = (int*)p;                p += (size_t)NN * 4;
    int* ind = (int*)p;                 p += (size_t)NN * 4;
    int* locex = (int*)p;               p += (size_t)NN * 4;
    int* partials = (int*)p;            p += (size_t)128 * 4;
    ushort* slots = (ushort*)p;         p += (size_t)NE * 2;

    hipMemsetAsync(outd, 0, (size_t)2 * NN * 4, stream);  // outd | ind contiguous

    k_count<<<2048, 256, 0, stream>>>(src, dst, outd, ind, slots);
    k_scan1<<<NBLK, SCAN_B, 0, stream>>>(ind, locex, partials);
    k_scan2<<<1, 128, 0, stream>>>(partials, rowptr + NN);
    k_scan3<<<NBLK, SCAN_B, 0, stream>>>(locex, partials, outd, ind, rowptr, onorm, inorm);
    k_scatter_wconv<<<SCAT_BLK + WCONV_BLK, 256, 0, stream>>>(src, dst, rowptr, slots, colidx,
                                                              W1, W2, Wt1, Wt2);

    k_embed<<<(NN * 64 + 255) / 256, 256, 0, stream>>>(feature, emb, onorm, hA);

    const int aggGrid = (NN * 64 + 255) / 256;
    const int gemmGrid = (NN + 383) / 384;
    // layer 0 (no W): hB = relu(agg(hA) * inorm) * onorm
    k_agg<0><<<aggGrid, 256, 0, stream>>>(rowptr, colidx, hA, inorm, onorm, hB);
    // layer 1: hA = hB @ W1 ; hB = relu(agg(hA) * inorm) * onorm
    k_gemm<<<gemmGrid, 512, 0, stream>>>(hB, Wt1, hA);
    k_agg<0><<<aggGrid, 256, 0, stream>>>(rowptr, colidx, hA, inorm, onorm, hB);
    // layer 2: hA = hB @ W2 ; hB = agg(hA) * inorm
    k_gemm<<<gemmGrid, 512, 0, stream>>>(hB, Wt2, hA);
    k_agg<1><<<aggGrid, 256, 0, stream>>>(rowptr, colidx, hA, inorm, onorm, hB);
    // pool per graph
    k_pool<<<NG, 256, 0, stream>>>(hB, gids, out);
}